// Round 10
// baseline (186.713 us; speedup 1.0000x reference)
//
#include <hip/hip_runtime.h>
#include <math.h>

// ConvCaps + EM routing, MI355X (gfx950).
// Shapes: caps (8,24,24,32,17) f32, trans (3,3,32,32,4,4) f32, out (8,11,11,32,17) f32.
// One 256-thread block per (b, n). Patch in LDS; votes recomputed per sweep
// (T slices L2-resident); mu/sigma fused via E[V^2]-mu^2; softmax over o via
// DPP butterfly per half-wave; packed fp32 (v_pk_*) math; exp2 domain with
// per-sweep Cmax shift.
// R10 = R9 + LDS diet for occupancy: red_s[3][32][33] (12.7KB) replaced by a
// single red1[32][33] (4.2KB) reduced with LDS atomics (wave1 plain-store,
// waves2-3 ds_add_f32, wave0 reads after barrier; (o*33+k)%32 bijective in o
// -> conflict-free). LDS 39168 -> 30720 B => 5 blocks/CU (20 waves/CU),
// +25% resident waves for latency hiding. Per-thread code unchanged vs R9.
// Operating point (hard-won): launch_bounds(256,4) -> 64-VGPR cap, no spill;
// (256,3) loses a resident block; attribute waves_per_eu ignored; >64 live
// regs => scratch catastrophe (R6/R7).

namespace {

constexpr int NH   = 11;    // output spatial dim
constexpr int NI   = 288;   // 3*3*32 input capsules per position
constexpr float LAM_   = 0.01f;
constexpr float EPS_   = 1e-8f;
constexpr float LOG2PI = 1.8378770664093453f;
constexpr float LOG2E  = 1.4426950408889634f;

typedef __attribute__((ext_vector_type(2))) float f32x2;

__device__ __forceinline__ f32x2 splat(float s) { return (f32x2){s, s}; }
__device__ __forceinline__ f32x2 vfma(f32x2 a, f32x2 b, f32x2 c) {
    return __builtin_elementwise_fma(a, b, c);
}

// ---- butterfly reductions over the 32 lanes of a half-wave ----
__device__ __forceinline__ float red32_max(float x) {
    int y;
    y = __builtin_amdgcn_update_dpp(0, __float_as_int(x), 0xB1, 0xF, 0xF, true);  // quad_perm xor1
    x = fmaxf(x, __int_as_float(y));
    y = __builtin_amdgcn_update_dpp(0, __float_as_int(x), 0x4E, 0xF, 0xF, true);  // quad_perm xor2
    x = fmaxf(x, __int_as_float(y));
    y = __builtin_amdgcn_update_dpp(0, __float_as_int(x), 0x141, 0xF, 0xF, true); // row_half_mirror
    x = fmaxf(x, __int_as_float(y));
    y = __builtin_amdgcn_update_dpp(0, __float_as_int(x), 0x140, 0xF, 0xF, true); // row_mirror
    x = fmaxf(x, __int_as_float(y));
    y = __builtin_amdgcn_ds_swizzle(__float_as_int(x), 0x401F);                   // xor16
    x = fmaxf(x, __int_as_float(y));
    return x;
}
__device__ __forceinline__ float red32_sum(float x) {
    int y;
    y = __builtin_amdgcn_update_dpp(0, __float_as_int(x), 0xB1, 0xF, 0xF, true);
    x += __int_as_float(y);
    y = __builtin_amdgcn_update_dpp(0, __float_as_int(x), 0x4E, 0xF, 0xF, true);
    x += __int_as_float(y);
    y = __builtin_amdgcn_update_dpp(0, __float_as_int(x), 0x141, 0xF, 0xF, true);
    x += __int_as_float(y);
    y = __builtin_amdgcn_update_dpp(0, __float_as_int(x), 0x140, 0xF, 0xF, true);
    x += __int_as_float(y);
    y = __builtin_amdgcn_ds_swizzle(__float_as_int(x), 0x401F);
    x += __int_as_float(y);
    return x;
}

__device__ __forceinline__ void load_T2(const float4* __restrict__ tp, f32x2 T2[8]) {
    float4 b0 = tp[0], b1 = tp[1], b2 = tp[2], b3 = tp[3];
    T2[0] = (f32x2){b0.x, b0.y};  T2[1] = (f32x2){b0.z, b0.w};
    T2[2] = (f32x2){b1.x, b1.y};  T2[3] = (f32x2){b1.z, b1.w};
    T2[4] = (f32x2){b2.x, b2.y};  T2[5] = (f32x2){b2.z, b2.w};
    T2[6] = (f32x2){b3.x, b3.y};  T2[7] = (f32x2){b3.z, b3.w};
}

// votes: V2[p*2+h] = sum_q P[p][q] * T2[q*2+h]   (r = 2h+e packed in f32x2)
__device__ __forceinline__ void votes_pk(const float4* __restrict__ Prow4,
                                         const f32x2 T2[8], f32x2 V2[8]) {
    float4 pr0 = Prow4[0], pr1 = Prow4[1], pr2 = Prow4[2], pr3 = Prow4[3];
#pragma unroll
    for (int h = 0; h < 2; ++h) {
        {
            f32x2 s = splat(pr0.x) * T2[h];
            s = vfma(splat(pr0.y), T2[2 + h], s);
            s = vfma(splat(pr0.z), T2[4 + h], s);
            V2[h] = vfma(splat(pr0.w), T2[6 + h], s);
        }
        {
            f32x2 s = splat(pr1.x) * T2[h];
            s = vfma(splat(pr1.y), T2[2 + h], s);
            s = vfma(splat(pr1.z), T2[4 + h], s);
            V2[2 + h] = vfma(splat(pr1.w), T2[6 + h], s);
        }
        {
            f32x2 s = splat(pr2.x) * T2[h];
            s = vfma(splat(pr2.y), T2[2 + h], s);
            s = vfma(splat(pr2.z), T2[4 + h], s);
            V2[4 + h] = vfma(splat(pr2.w), T2[6 + h], s);
        }
        {
            f32x2 s = splat(pr3.x) * T2[h];
            s = vfma(splat(pr3.y), T2[2 + h], s);
            s = vfma(splat(pr3.z), T2[4 + h], s);
            V2[6 + h] = vfma(splat(pr3.w), T2[6 + h], s);
        }
    }
}

// Finalize 8 p's with compile-time BASE so register indices stay static.
// r = the shared cross-wave accumulator row (sum of waves 1..3).
template<int BASE>
__device__ __forceinline__ float finalize_half(const f32x2* m1v, const f32x2* m2v,
        const float* __restrict__ r, float S, float rs, bool last,
        float* __restrict__ mu_dst, float* __restrict__ i2s_dst)
{
    float csum = 0.f;
#pragma unroll
    for (int p = 0; p < 8; ++p) {
        constexpr int B = BASE;
        float m1k = m1v[(B + p) >> 1][(B + p) & 1];
        float m2k = m2v[(B + p) >> 1][(B + p) & 1];
        float M1f = m1k + r[B + p];
        float M2f = m2k + r[16 + B + p];
        float m  = M1f * rs;
        float sg = (M2f - 2.f * m * M1f + m * m * S) * rs + EPS_;
        csum += __logf(sg);
        mu_dst[B + p] = m;
        if (!last) i2s_dst[B + p] = __fdividef(0.5f, sg) * LOG2E;  // exp2-scaled
    }
    return csum;
}

__global__ __launch_bounds__(256, 4)
void convcaps_em_kernel(const float* __restrict__ caps,
                        const float* __restrict__ Tm,
                        const float* __restrict__ bu_p,
                        const float* __restrict__ ba_p,
                        float* __restrict__ out)
{
    // LDS: 18432 + 1152 + 4224 + 2304 + 2304 + 128 + 2176 = 30720 B -> 5 blocks/CU
    __shared__ float pose_s[NI][16];     // poses
    __shared__ float act_s[NI];          // activations
    __shared__ float red1[32][33];       // shared cross-wave acc: m1[16], m2[16], sumR
    __shared__ float mu_s[32][18];       // stride 18: f32x2-aligned
    __shared__ float i2s_s[32][18];      // log2e/(2*sigma^2)
    __shared__ float C_s[32];            // (log(a+eps) - L - 8*log2pi) * log2e
    __shared__ float fin_s[32][17];      // final (mu,a) staging for coalesced store

    const int n  = blockIdx.x;           // 0..120
    const int b  = blockIdx.y;           // 0..7
    const int oy = n / NH;
    const int ox = n - oy * NH;
    const int t  = (int)threadIdx.x;
    const int o  = t & 31;               // output capsule
    const int ig = t >> 5;               // i-group 0..7
    const int wv = t >> 6;               // wave 0..3
    const int ln = t & 63;               // lane
    const int hi = ln >> 5;              // half within wave

    // ---- stage patch: 9 spatial cells x (32 caps * 17 floats) ----
    for (int idx = t; idx < 9 * 544; idx += 256) {
        int cell = idx / 544;
        int j    = idx - cell * 544;     // j = ic*17 + c
        int kx   = cell / 3;
        int ky   = cell - kx * 3;
        size_t src = ((((size_t)b * 24 + (2 * oy + kx)) * 24 + (2 * ox + ky)) * 32) * 17 + j;
        float v = caps[src];
        int ic = j / 17;
        int c  = j - ic * 17;
        int i  = cell * 32 + ic;
        if (c == 16) act_s[i] = v;
        else         pose_s[i][c] = v;
    }
    __syncthreads();

    const float beta_u = bu_p[0];
    const float beta_a = ba_p[0];
    const size_t oblk = ((((size_t)b * NH + oy) * NH + ox) * 32) * 17;

    f32x2 m1v[8], m2v[8];                // flat k = p*4+r, element k -> [k/2][k&1]
    float sR;

    // ================= sweep 0: ra = act/32, accumulate moments =================
#pragma unroll
    for (int j = 0; j < 8; ++j) { m1v[j] = splat(0.f); m2v[j] = splat(0.f); }
    sR = 0.f;
    {
        const float4* tptr = reinterpret_cast<const float4*>(Tm) + ((size_t)ig * 32 + o) * 4;
        for (int ii = 0; ii < NI / 8; ++ii, tptr += 1024) {
            const int i = ig + ii * 8;
            float ra = act_s[i] * (1.0f / 32.0f);
            f32x2 T2[8], V2[8];
            load_T2(tptr, T2);
            votes_pk(reinterpret_cast<const float4*>(&pose_s[i][0]), T2, V2);
            f32x2 ra2 = splat(ra);
#pragma unroll
            for (int j = 0; j < 8; ++j) {
                f32x2 rv = ra2 * V2[j];
                m1v[j] += rv;
                m2v[j] = vfma(rv, V2[j], m2v[j]);
            }
            sR += ra;
        }
    }

    for (int it = 0; it < 3; ++it) {
        // ---- combine ig pairs within wave ----
#pragma unroll
        for (int j = 0; j < 8; ++j) {
            m1v[j][0] += __shfl_xor(m1v[j][0], 32);
            m1v[j][1] += __shfl_xor(m1v[j][1], 32);
            m2v[j][0] += __shfl_xor(m2v[j][0], 32);
            m2v[j][1] += __shfl_xor(m2v[j][1], 32);
        }
        sR += __shfl_xor(sR, 32);

        // ---- cross-wave reduce into the single shared slot ----
        // wave 1: plain store; waves 2,3: LDS atomic add; wave 0: keeps regs.
        if (wv == 1 && ln < 32) {
#pragma unroll
            for (int j = 0; j < 8; ++j) {
                red1[o][2 * j]          = m1v[j][0];
                red1[o][2 * j + 1]      = m1v[j][1];
                red1[o][16 + 2 * j]     = m2v[j][0];
                red1[o][16 + 2 * j + 1] = m2v[j][1];
            }
            red1[o][32] = sR;
        }
        __syncthreads();
        if (wv >= 2 && ln < 32) {
#pragma unroll
            for (int j = 0; j < 8; ++j) {
                atomicAdd(&red1[o][2 * j],          m1v[j][0]);
                atomicAdd(&red1[o][2 * j + 1],      m1v[j][1]);
                atomicAdd(&red1[o][16 + 2 * j],     m2v[j][0]);
                atomicAdd(&red1[o][16 + 2 * j + 1], m2v[j][1]);
            }
            atomicAdd(&red1[o][32], sR);
        }
        __syncthreads();

        // ---- wave-0 finalize: mu, sigma, a (and C for it<2) ----
        if (wv == 0) {
            const bool last = (it == 2);
            const float* r = &red1[o][0];
            float S    = sR + r[32];
            float sumR = S + EPS_;
            float rs   = __fdividef(1.f, sumR);
            float* mu_dst  = last ? &fin_s[o][0] : &mu_s[o][0];
            float* i2s_dst = &i2s_s[o][0];
            float csum = (hi == 0)
                ? finalize_half<0>(m1v, m2v, r, S, rs, last, mu_dst, i2s_dst)
                : finalize_half<8>(m1v, m2v, r, S, rs, last, mu_dst, i2s_dst);
            csum *= 0.5f;
            float L = csum + __shfl_xor(csum, 32);     // after reconvergence
            float cost = sumR * (16.f * beta_u + L);
            float a = __fdividef(1.f, 1.f + __expf(-(LAM_ * (beta_a - cost))));
            if (hi == 0) {
                if (last) fin_s[o][16] = a;
                else      C_s[o] = (__logf(a + EPS_) - (L + 8.f * LOG2PI)) * LOG2E;
            }
        }
        if (it == 2) break;
        __syncthreads();

        // ==== fused sweep: q -> exp2 -> sum(o) -> ra -> moments ====
        const float Cc  = C_s[o];
        const float Ccs = Cc - red32_max(Cc);   // per-sweep shift (once, uniform in o-group)
        f32x2 MU2[8], IS2[8];
        {
            const f32x2* mrow = reinterpret_cast<const f32x2*>(&mu_s[o][0]);
            const f32x2* irow = reinterpret_cast<const f32x2*>(&i2s_s[o][0]);
#pragma unroll
            for (int j = 0; j < 8; ++j) { MU2[j] = mrow[j]; IS2[j] = irow[j]; }
        }

#pragma unroll
        for (int j = 0; j < 8; ++j) { m1v[j] = splat(0.f); m2v[j] = splat(0.f); }
        sR = 0.f;

        const float4* tptr = reinterpret_cast<const float4*>(Tm) + ((size_t)ig * 32 + o) * 4;
        for (int ii = 0; ii < NI / 8; ++ii, tptr += 1024) {
            const int i = ig + ii * 8;
            f32x2 T2[8], V2[8];
            load_T2(tptr, T2);
            votes_pk(reinterpret_cast<const float4*>(&pose_s[i][0]), T2, V2);

            f32x2 qa = splat(0.f), qb = splat(0.f);
#pragma unroll
            for (int j = 0; j < 8; j += 2) {
                f32x2 d0 = V2[j] - MU2[j];
                qa = vfma(d0 * d0, IS2[j], qa);
                f32x2 d1 = V2[j + 1] - MU2[j + 1];
                qb = vfma(d1 * d1, IS2[j + 1], qb);
            }
            f32x2 q2 = qa + qb;
            float e = exp2f(Ccs - (q2[0] + q2[1]));   // e <= 1 (Ccs <= 0, q >= 0)

            float sm = red32_sum(e);
            float ra = __fdividef(act_s[i] * e, sm);

            f32x2 ra2 = splat(ra);
#pragma unroll
            for (int j = 0; j < 8; ++j) {
                f32x2 rv = ra2 * V2[j];
                m1v[j] += rv;
                m2v[j] = vfma(rv, V2[j], m2v[j]);
            }
            sR += ra;
        }
    }

    // ---- coalesced epilogue: fin_s (32x17, packed) -> out ----
    __syncthreads();
    for (int k = t; k < 544; k += 256) {
        out[oblk + k] = (&fin_s[0][0])[k];
    }
}

} // namespace

extern "C" void kernel_launch(void* const* d_in, const int* in_sizes, int n_in,
                              void* d_out, int out_size, void* d_ws, size_t ws_size,
                              hipStream_t stream) {
    const float* caps = (const float*)d_in[0];   // (8,24,24,32,17)
    const float* Tm   = (const float*)d_in[1];   // (3,3,32,32,4,4)
    const float* bu   = (const float*)d_in[2];
    const float* ba   = (const float*)d_in[3];
    float* out        = (float*)d_out;           // (8,11,11,32,17)

    dim3 grid(121, 8);
    dim3 block(256);
    hipLaunchKernelGGL(convcaps_em_kernel, grid, block, 0, stream,
                       caps, Tm, bu, ba, out);
}

// Round 11
// 131.431 us; speedup vs baseline: 1.4206x; 1.4206x over previous
//
#include <hip/hip_runtime.h>
#include <math.h>

// ConvCaps + EM routing, MI355X (gfx950).
// Shapes: caps (8,24,24,32,17) f32, trans (3,3,32,32,4,4) f32, out (8,11,11,32,17) f32.
// One 256-thread block per (b, n). Patch in LDS; votes recomputed per sweep
// (T slices L2-resident); mu/sigma fused via E[V^2]-mu^2; softmax over o via
// DPP butterfly per half-wave; packed fp32 (v_pk_*) math.
// R11 = R9 verbatim (proven best: 148us rocprof / 131.5us wall).
// Operating-point ledger (all A/B'd on HW):
//  - launch_bounds(256,4): 64-VGPR cap, fits, 4 blocks/CU resident. BEST.
//  - launch_bounds(256,3): 128-VGPR cap but 3 blocks/CU -> -25% TLP (R8, 171us).
//  - >64 live regs (2-way interleave / deferred pipeline): scratch spill
//    catastrophe (R6: 169us, R7: 373us, 840MB HBM spill traffic).
//  - red_s via LDS atomics + 5-block capacity: grid is 968 blocks => all
//    co-resident at 4/CU already (3.78 waves/SIMD, TLP grid-capped); atomics
//    serialize LDS pipe (R10: 217us, VALUBusy 57->38%).
//  - Zero-register chain cuts that DID land: exp2 domain + per-sweep Cmax
//    shift (R9: -4us vs R5), DPP butterfly softmax + coalesced epilogue (R5).

namespace {

constexpr int NH   = 11;    // output spatial dim
constexpr int NI   = 288;   // 3*3*32 input capsules per position
constexpr float LAM_   = 0.01f;
constexpr float EPS_   = 1e-8f;
constexpr float LOG2PI = 1.8378770664093453f;
constexpr float LOG2E  = 1.4426950408889634f;

typedef __attribute__((ext_vector_type(2))) float f32x2;

__device__ __forceinline__ f32x2 splat(float s) { return (f32x2){s, s}; }
__device__ __forceinline__ f32x2 vfma(f32x2 a, f32x2 b, f32x2 c) {
    return __builtin_elementwise_fma(a, b, c);
}

// ---- butterfly reductions over the 32 lanes of a half-wave ----
__device__ __forceinline__ float red32_max(float x) {
    int y;
    y = __builtin_amdgcn_update_dpp(0, __float_as_int(x), 0xB1, 0xF, 0xF, true);  // quad_perm xor1
    x = fmaxf(x, __int_as_float(y));
    y = __builtin_amdgcn_update_dpp(0, __float_as_int(x), 0x4E, 0xF, 0xF, true);  // quad_perm xor2
    x = fmaxf(x, __int_as_float(y));
    y = __builtin_amdgcn_update_dpp(0, __float_as_int(x), 0x141, 0xF, 0xF, true); // row_half_mirror
    x = fmaxf(x, __int_as_float(y));
    y = __builtin_amdgcn_update_dpp(0, __float_as_int(x), 0x140, 0xF, 0xF, true); // row_mirror
    x = fmaxf(x, __int_as_float(y));
    y = __builtin_amdgcn_ds_swizzle(__float_as_int(x), 0x401F);                   // xor16
    x = fmaxf(x, __int_as_float(y));
    return x;
}
__device__ __forceinline__ float red32_sum(float x) {
    int y;
    y = __builtin_amdgcn_update_dpp(0, __float_as_int(x), 0xB1, 0xF, 0xF, true);
    x += __int_as_float(y);
    y = __builtin_amdgcn_update_dpp(0, __float_as_int(x), 0x4E, 0xF, 0xF, true);
    x += __int_as_float(y);
    y = __builtin_amdgcn_update_dpp(0, __float_as_int(x), 0x141, 0xF, 0xF, true);
    x += __int_as_float(y);
    y = __builtin_amdgcn_update_dpp(0, __float_as_int(x), 0x140, 0xF, 0xF, true);
    x += __int_as_float(y);
    y = __builtin_amdgcn_ds_swizzle(__float_as_int(x), 0x401F);
    x += __int_as_float(y);
    return x;
}

__device__ __forceinline__ void load_T2(const float4* __restrict__ tp, f32x2 T2[8]) {
    float4 b0 = tp[0], b1 = tp[1], b2 = tp[2], b3 = tp[3];
    T2[0] = (f32x2){b0.x, b0.y};  T2[1] = (f32x2){b0.z, b0.w};
    T2[2] = (f32x2){b1.x, b1.y};  T2[3] = (f32x2){b1.z, b1.w};
    T2[4] = (f32x2){b2.x, b2.y};  T2[5] = (f32x2){b2.z, b2.w};
    T2[6] = (f32x2){b3.x, b3.y};  T2[7] = (f32x2){b3.z, b3.w};
}

// votes: V2[p*2+h] = sum_q P[p][q] * T2[q*2+h]   (r = 2h+e packed in f32x2)
__device__ __forceinline__ void votes_pk(const float4* __restrict__ Prow4,
                                         const f32x2 T2[8], f32x2 V2[8]) {
    float4 pr0 = Prow4[0], pr1 = Prow4[1], pr2 = Prow4[2], pr3 = Prow4[3];
#pragma unroll
    for (int h = 0; h < 2; ++h) {
        {
            f32x2 s = splat(pr0.x) * T2[h];
            s = vfma(splat(pr0.y), T2[2 + h], s);
            s = vfma(splat(pr0.z), T2[4 + h], s);
            V2[h] = vfma(splat(pr0.w), T2[6 + h], s);
        }
        {
            f32x2 s = splat(pr1.x) * T2[h];
            s = vfma(splat(pr1.y), T2[2 + h], s);
            s = vfma(splat(pr1.z), T2[4 + h], s);
            V2[2 + h] = vfma(splat(pr1.w), T2[6 + h], s);
        }
        {
            f32x2 s = splat(pr2.x) * T2[h];
            s = vfma(splat(pr2.y), T2[2 + h], s);
            s = vfma(splat(pr2.z), T2[4 + h], s);
            V2[4 + h] = vfma(splat(pr2.w), T2[6 + h], s);
        }
        {
            f32x2 s = splat(pr3.x) * T2[h];
            s = vfma(splat(pr3.y), T2[2 + h], s);
            s = vfma(splat(pr3.z), T2[4 + h], s);
            V2[6 + h] = vfma(splat(pr3.w), T2[6 + h], s);
        }
    }
}

// Finalize 8 p's with compile-time BASE so register indices stay static.
template<int BASE>
__device__ __forceinline__ float finalize_half(const f32x2* m1v, const f32x2* m2v,
        const float* __restrict__ r0, const float* __restrict__ r1,
        const float* __restrict__ r2, float S, float rs, bool last,
        float* __restrict__ mu_dst, float* __restrict__ i2s_dst)
{
    float csum = 0.f;
#pragma unroll
    for (int p = 0; p < 8; ++p) {
        constexpr int B = BASE;
        float m1k = m1v[(B + p) >> 1][(B + p) & 1];
        float m2k = m2v[(B + p) >> 1][(B + p) & 1];
        float M1f = m1k + r0[B + p] + r1[B + p] + r2[B + p];
        float M2f = m2k + r0[16 + B + p] + r1[16 + B + p] + r2[16 + B + p];
        float m  = M1f * rs;
        float sg = (M2f - 2.f * m * M1f + m * m * S) * rs + EPS_;
        csum += __logf(sg);
        mu_dst[B + p] = m;
        if (!last) i2s_dst[B + p] = __fdividef(0.5f, sg) * LOG2E;  // exp2-scaled
    }
    return csum;
}

__global__ __launch_bounds__(256, 4)
void convcaps_em_kernel(const float* __restrict__ caps,
                        const float* __restrict__ Tm,
                        const float* __restrict__ bu_p,
                        const float* __restrict__ ba_p,
                        float* __restrict__ out)
{
    // LDS: 18432 + 1152 + 12672 + 2304 + 2304 + 128 + 2176 = 39168 B -> 4 blocks/CU
    __shared__ float pose_s[NI][16];     // poses
    __shared__ float act_s[NI];          // activations
    __shared__ float red_s[3][32][33];   // waves 1..3 partials: m1[16], m2[16], sumR
    __shared__ float mu_s[32][18];       // stride 18: f32x2-aligned
    __shared__ float i2s_s[32][18];      // log2e/(2*sigma^2)
    __shared__ float C_s[32];            // (log(a+eps) - L - 8*log2pi) * log2e
    __shared__ float fin_s[32][17];      // final (mu,a) staging for coalesced store

    const int n  = blockIdx.x;           // 0..120
    const int b  = blockIdx.y;           // 0..7
    const int oy = n / NH;
    const int ox = n - oy * NH;
    const int t  = (int)threadIdx.x;
    const int o  = t & 31;               // output capsule
    const int ig = t >> 5;               // i-group 0..7
    const int wv = t >> 6;               // wave 0..3
    const int ln = t & 63;               // lane
    const int hi = ln >> 5;              // half within wave

    // ---- stage patch: 9 spatial cells x (32 caps * 17 floats) ----
    for (int idx = t; idx < 9 * 544; idx += 256) {
        int cell = idx / 544;
        int j    = idx - cell * 544;     // j = ic*17 + c
        int kx   = cell / 3;
        int ky   = cell - kx * 3;
        size_t src = ((((size_t)b * 24 + (2 * oy + kx)) * 24 + (2 * ox + ky)) * 32) * 17 + j;
        float v = caps[src];
        int ic = j / 17;
        int c  = j - ic * 17;
        int i  = cell * 32 + ic;
        if (c == 16) act_s[i] = v;
        else         pose_s[i][c] = v;
    }
    __syncthreads();

    const float beta_u = bu_p[0];
    const float beta_a = ba_p[0];
    const size_t oblk = ((((size_t)b * NH + oy) * NH + ox) * 32) * 17;

    f32x2 m1v[8], m2v[8];                // flat k = p*4+r, element k -> [k/2][k&1]
    float sR;

    // ================= sweep 0: ra = act/32, accumulate moments =================
#pragma unroll
    for (int j = 0; j < 8; ++j) { m1v[j] = splat(0.f); m2v[j] = splat(0.f); }
    sR = 0.f;
    {
        const float4* tptr = reinterpret_cast<const float4*>(Tm) + ((size_t)ig * 32 + o) * 4;
        for (int ii = 0; ii < NI / 8; ++ii, tptr += 1024) {
            const int i = ig + ii * 8;
            float ra = act_s[i] * (1.0f / 32.0f);
            f32x2 T2[8], V2[8];
            load_T2(tptr, T2);
            votes_pk(reinterpret_cast<const float4*>(&pose_s[i][0]), T2, V2);
            f32x2 ra2 = splat(ra);
#pragma unroll
            for (int j = 0; j < 8; ++j) {
                f32x2 rv = ra2 * V2[j];
                m1v[j] += rv;
                m2v[j] = vfma(rv, V2[j], m2v[j]);
            }
            sR += ra;
        }
    }

    for (int it = 0; it < 3; ++it) {
        // ---- combine ig pairs within wave ----
#pragma unroll
        for (int j = 0; j < 8; ++j) {
            m1v[j][0] += __shfl_xor(m1v[j][0], 32);
            m1v[j][1] += __shfl_xor(m1v[j][1], 32);
            m2v[j][0] += __shfl_xor(m2v[j][0], 32);
            m2v[j][1] += __shfl_xor(m2v[j][1], 32);
        }
        sR += __shfl_xor(sR, 32);
        if (wv > 0 && ln < 32) {
#pragma unroll
            for (int j = 0; j < 8; ++j) {
                red_s[wv - 1][o][2 * j]          = m1v[j][0];
                red_s[wv - 1][o][2 * j + 1]      = m1v[j][1];
                red_s[wv - 1][o][16 + 2 * j]     = m2v[j][0];
                red_s[wv - 1][o][16 + 2 * j + 1] = m2v[j][1];
            }
            red_s[wv - 1][o][32] = sR;
        }
        __syncthreads();

        // ---- wave-0 finalize: mu, sigma, a (and C for it<2) ----
        if (wv == 0) {
            const bool last = (it == 2);
            const float* r0 = &red_s[0][o][0];
            const float* r1 = &red_s[1][o][0];
            const float* r2 = &red_s[2][o][0];
            float S    = sR + r0[32] + r1[32] + r2[32];
            float sumR = S + EPS_;
            float rs   = __fdividef(1.f, sumR);
            float* mu_dst  = last ? &fin_s[o][0] : &mu_s[o][0];
            float* i2s_dst = &i2s_s[o][0];
            float csum = (hi == 0)
                ? finalize_half<0>(m1v, m2v, r0, r1, r2, S, rs, last, mu_dst, i2s_dst)
                : finalize_half<8>(m1v, m2v, r0, r1, r2, S, rs, last, mu_dst, i2s_dst);
            csum *= 0.5f;
            float L = csum + __shfl_xor(csum, 32);     // after reconvergence
            float cost = sumR * (16.f * beta_u + L);
            float a = __fdividef(1.f, 1.f + __expf(-(LAM_ * (beta_a - cost))));
            if (hi == 0) {
                if (last) fin_s[o][16] = a;
                else      C_s[o] = (__logf(a + EPS_) - (L + 8.f * LOG2PI)) * LOG2E;
            }
        }
        if (it == 2) break;
        __syncthreads();

        // ==== fused sweep: q -> exp2 -> sum(o) -> ra -> moments ====
        const float Cc  = C_s[o];
        const float Ccs = Cc - red32_max(Cc);   // per-sweep shift (once, uniform in o-group)
        f32x2 MU2[8], IS2[8];
        {
            const f32x2* mrow = reinterpret_cast<const f32x2*>(&mu_s[o][0]);
            const f32x2* irow = reinterpret_cast<const f32x2*>(&i2s_s[o][0]);
#pragma unroll
            for (int j = 0; j < 8; ++j) { MU2[j] = mrow[j]; IS2[j] = irow[j]; }
        }

#pragma unroll
        for (int j = 0; j < 8; ++j) { m1v[j] = splat(0.f); m2v[j] = splat(0.f); }
        sR = 0.f;

        const float4* tptr = reinterpret_cast<const float4*>(Tm) + ((size_t)ig * 32 + o) * 4;
        for (int ii = 0; ii < NI / 8; ++ii, tptr += 1024) {
            const int i = ig + ii * 8;
            f32x2 T2[8], V2[8];
            load_T2(tptr, T2);
            votes_pk(reinterpret_cast<const float4*>(&pose_s[i][0]), T2, V2);

            f32x2 qa = splat(0.f), qb = splat(0.f);
#pragma unroll
            for (int j = 0; j < 8; j += 2) {
                f32x2 d0 = V2[j] - MU2[j];
                qa = vfma(d0 * d0, IS2[j], qa);
                f32x2 d1 = V2[j + 1] - MU2[j + 1];
                qb = vfma(d1 * d1, IS2[j + 1], qb);
            }
            f32x2 q2 = qa + qb;
            float e = exp2f(Ccs - (q2[0] + q2[1]));   // e <= 1 (Ccs <= 0, q >= 0)

            float sm = red32_sum(e);
            float ra = __fdividef(act_s[i] * e, sm);

            f32x2 ra2 = splat(ra);
#pragma unroll
            for (int j = 0; j < 8; ++j) {
                f32x2 rv = ra2 * V2[j];
                m1v[j] += rv;
                m2v[j] = vfma(rv, V2[j], m2v[j]);
            }
            sR += ra;
        }
    }

    // ---- coalesced epilogue: fin_s (32x17, packed) -> out ----
    __syncthreads();
    for (int k = t; k < 544; k += 256) {
        out[oblk + k] = (&fin_s[0][0])[k];
    }
}

} // namespace

extern "C" void kernel_launch(void* const* d_in, const int* in_sizes, int n_in,
                              void* d_out, int out_size, void* d_ws, size_t ws_size,
                              hipStream_t stream) {
    const float* caps = (const float*)d_in[0];   // (8,24,24,32,17)
    const float* Tm   = (const float*)d_in[1];   // (3,3,32,32,4,4)
    const float* bu   = (const float*)d_in[2];
    const float* ba   = (const float*)d_in[3];
    float* out        = (float*)d_out;           // (8,11,11,32,17)

    dim3 grid(121, 8);
    dim3 block(256);
    hipLaunchKernelGGL(convcaps_em_kernel, grid, block, 0, stream,
                       caps, Tm, bu, ba, out);
}